// Round 13
// baseline (63.149 us; speedup 1.0000x reference)
//
#include <hip/hip_runtime.h>

typedef float f32x4 __attribute__((ext_vector_type(4)));
typedef float f32x2 __attribute__((ext_vector_type(2)));

namespace {
constexpr int BATCH = 32;
constexpr int H = 192;
constexpr int W = 192;
constexpr int HW = H * W;
constexpr int NCLS = 25;
constexpr int LUTN = 26 * 25;   // sk[tap*26 + lab], col 25 = 0 sentinel

constexpr int OFF_PRED   = 0;
constexpr int OFF_MASKF  = BATCH * 3 * HW;
constexpr int OFF_OMAF   = OFF_MASKF + BATCH * NCLS * HW;
constexpr int OFF_ATTN   = OFF_OMAF + BATCH * HW;
constexpr int OFF_MASKB  = OFF_ATTN + BATCH * HW;
constexpr int OFF_OMAB   = OFF_MASKB + BATCH * NCLS * HW;
constexpr int OFF_OMATTN = OFF_OMAB + BATCH * HW;

constexpr int TY = 12;           // tile = full width x 12 rows
constexpr int SROWS = TY + 4;    // 16 packed-appear rows
constexpr int SW = W + 8;        // 200 floats/row (4-px pad each side)
constexpr int GPR = W / 4;       // 48 four-px groups per row
constexpr int NTHR = GPR * TY;   // 576 threads (9 waves)
constexpr int YT = H / TY;       // 16
constexpr int NBLK = BATCH * YT; // 512 blocks = 2/CU
constexpr int LROWS = TY + 8;    // 20 staged label rows
constexpr int LW32 = 50;         // u32/row: 4B pad | 192 labels (u8) | 4B pad
constexpr float SENT = 2.0f * NCLS;
constexpr unsigned SENTB = 0x19191919u;  // label 25 in every byte
}  // namespace

__device__ __forceinline__ void nt_store4(float* p, float a, float b, float c, float d) {
    f32x4 v = {a, b, c, d};
    __builtin_nontemporal_store(v, reinterpret_cast<f32x4*>(p));
}

__device__ __forceinline__ void f4_win12(float w[12], const float* __restrict__ row, int xb) {
    if (xb >= 4) {
        const float4 a = *reinterpret_cast<const float4*>(row + xb - 4);
        w[0] = a.x; w[1] = a.y; w[2] = a.z; w[3] = a.w;
    } else {
        w[0] = 0.f; w[1] = 0.f; w[2] = 0.f; w[3] = 0.f;
    }
    {
        const float4 c = *reinterpret_cast<const float4*>(row + xb);
        w[4] = c.x; w[5] = c.y; w[6] = c.z; w[7] = c.w;
    }
    if (xb <= W - 8) {
        const float4 e = *reinterpret_cast<const float4*>(row + xb + 4);
        w[8] = e.x; w[9] = e.y; w[10] = e.z; w[11] = e.w;
    } else {
        w[8] = 0.f; w[9] = 0.f; w[10] = 0.f; w[11] = 0.f;
    }
}

// Shared math tail for one dy row: decode packed appear+label, gather, fma.
__device__ __forceinline__ void conv_row_math(
    const float (*P)[SW], const float* __restrict__ sk,
    int srow, int g_i, int dy,
    const float v0[12], const float v1[12], const float v2[12], float acc[3][4])
{
    float pw[12];
    *reinterpret_cast<f32x4*>(&pw[0]) = *reinterpret_cast<const f32x4*>(&P[srow][4 * g_i]);
    *reinterpret_cast<f32x4*>(&pw[4]) = *reinterpret_cast<const f32x4*>(&P[srow][4 * g_i + 4]);
    *reinterpret_cast<f32x4*>(&pw[8]) = *reinterpret_cast<const f32x4*>(&P[srow][4 * g_i + 8]);
    int lw[12];
    float aw[12];
#pragma unroll
    for (int j = 2; j < 10; ++j) {
        const int l = (int)(pw[j] * 0.5f);
        lw[j] = l;
        aw[j] = pw[j] - 2.f * (float)l;
    }
#pragma unroll
    for (int dx = 0; dx < 5; ++dx) {
        const int base = (dy * 5 + dx) * 26;
#pragma unroll
        for (int i = 0; i < 4; ++i) {
            const int li = i + dx + 2;
            const float w = aw[li] * sk[base + lw[li]];
            acc[0][i] = fmaf(w, v0[li], acc[0][i]);
            acc[1][i] = fmaf(w, v1[li], acc[1][i]);
            acc[2][i] = fmaf(w, v2[li], acc[2][i]);
        }
    }
}

// F image: plain conv, no stores.
__device__ __forceinline__ void conv_img_f(
    const float (*P)[SW], const float* __restrict__ im, const float* __restrict__ sk,
    int b, int y, int x, int r_i, int g_i, float acc[3][4])
{
    for (int dy = 0; dy < 5; ++dy) {
        const int yy = y + dy - 2;
        if (yy < 0 || yy >= H) continue;
        const int imo = b * (6 * HW) + 3 * HW + yy * W;
        float v0[12], v1[12], v2[12];
        f4_win12(v0, im + imo, x);
        f4_win12(v1, im + imo + HW, x);
        f4_win12(v2, im + imo + 2 * HW, x);
        conv_row_math(P, sk, r_i + dy, g_i, dy, v0, v1, v2, acc);
    }
}

// B image: software-pipelined — dy+1's loads issue BEFORE dy's stores, so no
// load-wait ever forces a store drain (vmcnt FIFO retires in order).
__device__ __forceinline__ void conv_img_b(
    const float (*P)[SW], const float* __restrict__ im, const float* __restrict__ sk,
    const int lab4[4], float* __restrict__ mbase,
    int b, int y, int x, int r_i, int g_i, float acc[3][4])
{
    const int imbase = b * (6 * HW) + 3 * HW;
    float v0[2][12], v1[2][12], v2[2][12];
    {   // preload dy=0 (yy = y-2 < H always; guard only low edge)
        const int yy = y - 2;
        if (yy >= 0) {
            f4_win12(v0[0], im + imbase + yy * W, x);
            f4_win12(v1[0], im + imbase + HW + yy * W, x);
            f4_win12(v2[0], im + imbase + 2 * HW + yy * W, x);
        }
    }
#pragma unroll
    for (int dy = 0; dy < 5; ++dy) {
        const int cur = dy & 1;
        const int nxt = cur ^ 1;
        const int yy = y + dy - 2;
        const bool rowok = (yy >= 0 && yy < H);

        // issue NEXT iteration's loads first (ahead of this iteration's stores)
        if (dy < 4) {
            const int yn = y + dy - 1;
            if (yn >= 0 && yn < H) {
                f4_win12(v0[nxt], im + imbase + yn * W, x);
                f4_win12(v1[nxt], im + imbase + HW + yn * W, x);
                f4_win12(v2[nxt], im + imbase + 2 * HW + yn * W, x);
            }
        }

        // this iteration's 5 mask-plane stores
#pragma unroll
        for (int kk = 0; kk < 5; ++kk) {
            const int k = dy * 5 + kk;
            nt_store4(mbase + k * HW, lab4[0] == k ? 1.f : 0.f, lab4[1] == k ? 1.f : 0.f,
                      lab4[2] == k ? 1.f : 0.f, lab4[3] == k ? 1.f : 0.f);
        }

        if (rowok)
            conv_row_math(P, sk, r_i + dy, g_i, dy, v0[cur], v1[cur], v2[cur], acc);
    }
}

__global__ __launch_bounds__(NTHR) void k_fused(
    const float* __restrict__ imF, const float* __restrict__ imB,
    const int* __restrict__ labF, const int* __restrict__ labB,
    const float* __restrict__ mk, float* __restrict__ out)
{
    __shared__ float sk[LUTN];
    __shared__ unsigned labs[2][LROWS][LW32];   // u8-packed labels, sentinel-padded
    __shared__ float pF[SROWS][SW];
    __shared__ float pB[SROWS][SW];

    // XCD-aware bijective swizzle (NBLK % 8 == 0).
    const int o = blockIdx.x;
    const int blk = (o & 7) * (NBLK / 8) + (o >> 3);
    const int by = blk % YT;
    const int b  = blk / YT;
    const int y0 = by * TY;
    const int t = threadIdx.x;

    // ---- Stage LUT + both label tiles (only global LOADS; no stores yet) ----
    for (int i = t; i < LUTN; i += NTHR) {
        const int tap = i / 26;
        const int l = i - tap * 26;
        sk[i] = (l < NCLS) ? mk[l * 25 + tap] : 0.0f;
    }
    for (int u = t; u < 2 * LROWS * LW32; u += NTHR) {
        const int img = u / (LROWS * LW32);
        const int rem = u - img * (LROWS * LW32);
        const int row = rem / LW32;
        const int gw = rem - row * LW32;
        const int yg = y0 - 4 + row;
        unsigned v = SENTB;
        if (yg >= 0 && yg < H && gw > 0 && gw < LW32 - 1) {
            const int* lp = (img ? labB : labF) + b * HW + yg * W + 4 * (gw - 1);
            const int4 l4 = *reinterpret_cast<const int4*>(lp);
            v = (unsigned)(l4.x & 255) | ((unsigned)(l4.y & 255) << 8) |
                ((unsigned)(l4.z & 255) << 16) | ((unsigned)(l4.w & 255) << 24);
        }
        labs[img][row][gw] = v;
    }
    __syncthreads();

    const int r_i = t / GPR;   // 0..11
    const int g_i = t % GPR;   // 0..47
    const int y = y0 + r_i;
    const int x = 4 * g_i;
    const int pix = b * HW + y * W + x;

    // ================= Phase A: zero vmcnt loads =================
    const unsigned cf = labs[0][r_i + 4][g_i + 1];
    const unsigned cb = labs[1][r_i + 4][g_i + 1];
    const int lfa[4] = {(int)(cf & 255), (int)((cf >> 8) & 255),
                        (int)((cf >> 16) & 255), (int)((cf >> 24) & 255)};
    const int lba[4] = {(int)(cb & 255), (int)((cb >> 8) & 255),
                        (int)((cb >> 16) & 255), (int)((cb >> 24) & 255)};
    float* __restrict__ mfb = out + OFF_MASKF + b * (NCLS * HW) + y * W + x;

    // A2: own-group seg from LDS labels, F-mask stores interleaved (5/dy).
    float segf[4] = {}, segb[4] = {};
#pragma unroll
    for (int dy = 0; dy < 5; ++dy) {
#pragma unroll
        for (int kk = 0; kk < 5; ++kk) {
            const int k = dy * 5 + kk;
            nt_store4(mfb + k * HW, lfa[0] == k ? 1.f : 0.f, lfa[1] == k ? 1.f : 0.f,
                      lfa[2] == k ? 1.f : 0.f, lfa[3] == k ? 1.f : 0.f);
        }
        const int sr = r_i + dy + 2;   // staged row for global y+dy-2
        const unsigned f0 = labs[0][sr][g_i], f1 = labs[0][sr][g_i + 1],
                       f2 = labs[0][sr][g_i + 2];
        const unsigned h0 = labs[1][sr][g_i], h1 = labs[1][sr][g_i + 1],
                       h2 = labs[1][sr][g_i + 2];
        int lwF[8], lwB[8];
#pragma unroll
        for (int j = 0; j < 8; ++j) {
            const int bo = 2 + j;
            const unsigned wf = (bo < 4) ? f0 : (bo < 8 ? f1 : f2);
            const unsigned wb = (bo < 4) ? h0 : (bo < 8 ? h1 : h2);
            const int sh = (bo & 3) * 8;
            lwF[j] = (int)((wf >> sh) & 255);
            lwB[j] = (int)((wb >> sh) & 255);
        }
#pragma unroll
        for (int dx = 0; dx < 5; ++dx) {
            const int base = (dy * 5 + dx) * 26;
#pragma unroll
            for (int i = 0; i < 4; ++i) {
                segf[i] += sk[base + lwF[i + dx]];
                segb[i] += sk[base + lwB[i + dx]];
            }
        }
    }

    // A3: appear -> packed LDS; aux outputs (nt); attn in registers.
    float my_at[4];
    {
        f32x4 pf, pb;
        float af[4], ab[4];
#pragma unroll
        for (int i = 0; i < 4; ++i) {
            af[i] = fmaxf(1.f - fmaxf(segf[i] - 1.f, 0.f), 0.f);
            ab[i] = fmaxf(1.f - fmaxf(segb[i] - 1.f, 0.f), 0.f);
            pf[i] = 2.f * (float)lfa[i] + af[i];
            pb[i] = 2.f * (float)lba[i] + ab[i];
            const float scf = 1.f - fmaxf(1.f - segf[i], 0.f);
            const float scb = 1.f - fmaxf(1.f - segb[i], 0.f);
            my_at[i] = (scf + 1e-5f) / (scf + scb + 2e-5f);
        }
        *reinterpret_cast<f32x4*>(&pF[r_i + 2][4 + x]) = pf;
        *reinterpret_cast<f32x4*>(&pB[r_i + 2][4 + x]) = pb;
        nt_store4(out + OFF_OMAF + pix, 1.f - af[0], 1.f - af[1], 1.f - af[2], 1.f - af[3]);
        nt_store4(out + OFF_OMAB + pix, 1.f - ab[0], 1.f - ab[1], 1.f - ab[2], 1.f - ab[3]);
        nt_store4(out + OFF_ATTN + pix, my_at[0], my_at[1], my_at[2], my_at[3]);
        nt_store4(out + OFF_OMATTN + pix, 1.f - my_at[0], 1.f - my_at[1], 1.f - my_at[2],
                  1.f - my_at[3]);
    }

    // A4: halo from LDS labels — 384 threads, one 2-px unit each (rows {0,1,14,15}).
    if (t < 384) {
        const int hrow = t / 96;
        const int row = (hrow < 2) ? hrow : hrow + TY;   // {0,1,14,15}
        const int hg = t % 96;
        const int xs = 2 * hg;
        const int q = xs >> 2;
        const int off0 = (xs & 3) + 2;
        float sf[2] = {0.f, 0.f}, sb[2] = {0.f, 0.f};
#pragma unroll
        for (int dyh = 0; dyh < 5; ++dyh) {
            const int sr = row + dyh;
            const unsigned f0 = labs[0][sr][q], f1 = labs[0][sr][q + 1],
                           f2 = labs[0][sr][q + 2];
            const unsigned h0 = labs[1][sr][q], h1 = labs[1][sr][q + 1],
                           h2 = labs[1][sr][q + 2];
            int lf6[6], lb6[6];
#pragma unroll
            for (int j = 0; j < 6; ++j) {
                const int bo = off0 + j;
                const unsigned wf = (bo < 4) ? f0 : (bo < 8 ? f1 : f2);
                const unsigned wb = (bo < 4) ? h0 : (bo < 8 ? h1 : h2);
                const int sh = (bo & 3) * 8;
                lf6[j] = (int)((wf >> sh) & 255);
                lb6[j] = (int)((wb >> sh) & 255);
            }
#pragma unroll
            for (int dx = 0; dx < 5; ++dx) {
                const int base = (dyh * 5 + dx) * 26;
                sf[0] += sk[base + lf6[dx]];
                sf[1] += sk[base + lf6[dx + 1]];
                sb[0] += sk[base + lb6[dx]];
                sb[1] += sk[base + lb6[dx + 1]];
            }
        }
        const unsigned cf2 = labs[0][row + 2][q + 1];
        const unsigned cb2 = labs[1][row + 2][q + 1];
        const int shc = (xs & 3) * 8;
        const int lf2[2] = {(int)((cf2 >> shc) & 255), (int)((cf2 >> (shc + 8)) & 255)};
        const int lb2[2] = {(int)((cb2 >> shc) & 255), (int)((cb2 >> (shc + 8)) & 255)};
        f32x2 pf2, pb2;
#pragma unroll
        for (int i = 0; i < 2; ++i) {
            const float af = fmaxf(1.f - fmaxf(sf[i] - 1.f, 0.f), 0.f);
            const float ab = fmaxf(1.f - fmaxf(sb[i] - 1.f, 0.f), 0.f);
            pf2[i] = 2.f * (float)lf2[i] + af;
            pb2[i] = 2.f * (float)lb2[i] + ab;
        }
        *reinterpret_cast<f32x2*>(&pF[row][4 + xs]) = pf2;
        *reinterpret_cast<f32x2*>(&pB[row][4 + xs]) = pb2;
    }

    // A5: sentinel side pads.
    if (t < 64) {
        const int arr = t & 1, side = (t >> 1) & 1, row = t >> 2;
        f32x4 s = {SENT, SENT, SENT, SENT};
        float* dst = arr ? &pB[row][side ? W + 4 : 0] : &pF[row][side ? W + 4 : 0];
        *reinterpret_cast<f32x4*>(dst) = s;
    }

    // ===== lgkm-only barrier: nt stores keep draining across it =====
    __builtin_amdgcn_sched_barrier(0);
    asm volatile("s_waitcnt lgkmcnt(0)" ::: "memory");
    __builtin_amdgcn_s_barrier();
    __builtin_amdgcn_sched_barrier(0);
    asm volatile("" ::: "memory");

    // ================= Phase B =================
    float accF[3][4] = {};
    float accB[3][4] = {};
    conv_img_f(pF, imF, sk, b, y, x, r_i, g_i, accF);
    conv_img_b(pB, imB, sk, lba, out + OFF_MASKB + b * (NCLS * HW) + y * W + x,
               b, y, x, r_i, g_i, accB);

    float* pout = out + OFF_PRED + b * (3 * HW) + y * W + x;
#pragma unroll
    for (int c = 0; c < 3; ++c) {
        float p[4];
#pragma unroll
        for (int i = 0; i < 4; ++i)
            p[i] = my_at[i] * accF[c][i] + (1.f - my_at[i]) * accB[c][i];
        nt_store4(pout + c * HW, p[0], p[1], p[2], p[3]);
    }
}

extern "C" void kernel_launch(void* const* d_in, const int* in_sizes, int n_in,
                              void* d_out, int out_size, void* d_ws, size_t ws_size,
                              hipStream_t stream) {
    const float* imF  = (const float*)d_in[0];
    const float* imB  = (const float*)d_in[1];
    const int*   labF = (const int*)d_in[2];
    const int*   labB = (const int*)d_in[3];
    const float* mk   = (const float*)d_in[4];
    float* out = (float*)d_out;

    k_fused<<<NBLK, NTHR, 0, stream>>>(imF, imB, labF, labB, mk, out);
}

// Round 14
// 61.081 us; speedup vs baseline: 1.0339x; 1.0339x over previous
//
#include <hip/hip_runtime.h>

typedef float f32x4 __attribute__((ext_vector_type(4)));
typedef float f32x2 __attribute__((ext_vector_type(2)));

namespace {
constexpr int BATCH = 32;
constexpr int H = 192;
constexpr int W = 192;
constexpr int HW = H * W;
constexpr int NCLS = 25;
constexpr int LUTN = 26 * 25;   // sk[tap*26 + lab], col 25 = 0 sentinel

constexpr int OFF_PRED   = 0;
constexpr int OFF_MASKF  = BATCH * 3 * HW;
constexpr int OFF_OMAF   = OFF_MASKF + BATCH * NCLS * HW;
constexpr int OFF_ATTN   = OFF_OMAF + BATCH * HW;
constexpr int OFF_MASKB  = OFF_ATTN + BATCH * HW;
constexpr int OFF_OMAB   = OFF_MASKB + BATCH * NCLS * HW;
constexpr int OFF_OMATTN = OFF_OMAB + BATCH * HW;

constexpr int TY = 12;           // tile = full width x 12 rows
constexpr int SROWS = TY + 4;    // 16 packed-appear rows
constexpr int SW = W + 8;        // 200 floats/row (4-px pad each side)
constexpr int GPR = W / 4;       // 48 four-px groups per row
constexpr int NTHR = GPR * TY;   // 576 threads (9 waves)
constexpr int YT = H / TY;       // 16
constexpr int NBLK = BATCH * YT; // 512 blocks = 2/CU
constexpr int LROWS = TY + 8;    // 20 staged label rows
constexpr int LW32 = 50;         // u32/row: 4B pad | 192 labels (u8) | 4B pad
constexpr float SENT = 2.0f * NCLS;
constexpr unsigned SENTB = 0x19191919u;  // label 25 in every byte
}  // namespace

__device__ __forceinline__ void nt_store4(float* p, float a, float b, float c, float d) {
    f32x4 v = {a, b, c, d};
    __builtin_nontemporal_store(v, reinterpret_cast<f32x4*>(p));
}

__device__ __forceinline__ void f4_win12(float w[12], const float* __restrict__ row, int xb) {
    if (xb >= 4) {
        const float4 a = *reinterpret_cast<const float4*>(row + xb - 4);
        w[0] = a.x; w[1] = a.y; w[2] = a.z; w[3] = a.w;
    } else {
        w[0] = 0.f; w[1] = 0.f; w[2] = 0.f; w[3] = 0.f;
    }
    {
        const float4 c = *reinterpret_cast<const float4*>(row + xb);
        w[4] = c.x; w[5] = c.y; w[6] = c.z; w[7] = c.w;
    }
    if (xb <= W - 8) {
        const float4 e = *reinterpret_cast<const float4*>(row + xb + 4);
        w[8] = e.x; w[9] = e.y; w[10] = e.z; w[11] = e.w;
    } else {
        w[8] = 0.f; w[9] = 0.f; w[10] = 0.f; w[11] = 0.f;
    }
}

// Conv one image; STORES=true interleaves that image's 25 mask-plane nt stores.
template <bool STORES>
__device__ __forceinline__ void conv_img(
    const float (*P)[SW], const float* __restrict__ im,
    const float* __restrict__ sk, const int lab4[4],
    float* __restrict__ mbase,
    int b, int y, int x, int r_i, int g_i, float acc[3][4])
{
    for (int dy = 0; dy < 5; ++dy) {
        const int yy = y + dy - 2;
        const bool rowok = (yy >= 0 && yy < H);

        float pw[12], v0[12], v1[12], v2[12];
        if (rowok) {
            const int srow = r_i + dy;
            *reinterpret_cast<f32x4*>(&pw[0]) =
                *reinterpret_cast<const f32x4*>(&P[srow][4 * g_i]);
            *reinterpret_cast<f32x4*>(&pw[4]) =
                *reinterpret_cast<const f32x4*>(&P[srow][4 * g_i + 4]);
            *reinterpret_cast<f32x4*>(&pw[8]) =
                *reinterpret_cast<const f32x4*>(&P[srow][4 * g_i + 8]);
            const int imo = b * (6 * HW) + 3 * HW + yy * W;
            f4_win12(v0, im + imo, x);
            f4_win12(v1, im + imo + HW, x);
            f4_win12(v2, im + imo + 2 * HW, x);
        }

        if (STORES) {
#pragma unroll
            for (int kk = 0; kk < 5; ++kk) {
                const int k = dy * 5 + kk;
                nt_store4(mbase + k * HW, lab4[0] == k ? 1.f : 0.f, lab4[1] == k ? 1.f : 0.f,
                          lab4[2] == k ? 1.f : 0.f, lab4[3] == k ? 1.f : 0.f);
            }
        }

        if (rowok) {
            int lw[12];
            float aw[12];
#pragma unroll
            for (int j = 2; j < 10; ++j) {
                const int l = (int)(pw[j] * 0.5f);
                lw[j] = l;
                aw[j] = pw[j] - 2.f * (float)l;
            }
#pragma unroll
            for (int dx = 0; dx < 5; ++dx) {
                const int base = (dy * 5 + dx) * 26;
#pragma unroll
                for (int i = 0; i < 4; ++i) {
                    const int li = i + dx + 2;
                    const float w = aw[li] * sk[base + lw[li]];
                    acc[0][i] = fmaf(w, v0[li], acc[0][i]);
                    acc[1][i] = fmaf(w, v1[li], acc[1][i]);
                    acc[2][i] = fmaf(w, v2[li], acc[2][i]);
                }
            }
        }
    }
}

__global__ __launch_bounds__(NTHR) void k_fused(
    const float* __restrict__ imF, const float* __restrict__ imB,
    const int* __restrict__ labF, const int* __restrict__ labB,
    const float* __restrict__ mk, float* __restrict__ out)
{
    __shared__ float sk[LUTN];
    __shared__ unsigned labs[2][LROWS][LW32];   // u8-packed labels, sentinel-padded
    __shared__ float pF[SROWS][SW];
    __shared__ float pB[SROWS][SW];

    // XCD-aware bijective swizzle (NBLK % 8 == 0).
    const int o = blockIdx.x;
    const int blk = (o & 7) * (NBLK / 8) + (o >> 3);
    const int by = blk % YT;
    const int b  = blk / YT;
    const int y0 = by * TY;
    const int t = threadIdx.x;

    // ---- Stage LUT + both label tiles (only global LOADS; no stores yet) ----
    for (int i = t; i < LUTN; i += NTHR) {
        const int tap = i / 26;
        const int l = i - tap * 26;
        sk[i] = (l < NCLS) ? mk[l * 25 + tap] : 0.0f;
    }
    for (int u = t; u < 2 * LROWS * LW32; u += NTHR) {
        const int img = u / (LROWS * LW32);
        const int rem = u - img * (LROWS * LW32);
        const int row = rem / LW32;
        const int gw = rem - row * LW32;
        const int yg = y0 - 4 + row;
        unsigned v = SENTB;
        if (yg >= 0 && yg < H && gw > 0 && gw < LW32 - 1) {
            const int* lp = (img ? labB : labF) + b * HW + yg * W + 4 * (gw - 1);
            const int4 l4 = *reinterpret_cast<const int4*>(lp);
            v = (unsigned)(l4.x & 255) | ((unsigned)(l4.y & 255) << 8) |
                ((unsigned)(l4.z & 255) << 16) | ((unsigned)(l4.w & 255) << 24);
        }
        labs[img][row][gw] = v;
    }
    __syncthreads();

    const int r_i = t / GPR;   // 0..11
    const int g_i = t % GPR;   // 0..47
    const int y = y0 + r_i;
    const int x = 4 * g_i;
    const int pix = b * HW + y * W + x;

    // ================= Phase A: zero vmcnt loads =================
    // Center labels from LDS: global row y = y0+r_i -> staged row r_i+4.
    const unsigned cf = labs[0][r_i + 4][g_i + 1];
    const unsigned cb = labs[1][r_i + 4][g_i + 1];
    const int lfa[4] = {(int)(cf & 255), (int)((cf >> 8) & 255),
                        (int)((cf >> 16) & 255), (int)((cf >> 24) & 255)};
    const int lba[4] = {(int)(cb & 255), (int)((cb >> 8) & 255),
                        (int)((cb >> 16) & 255), (int)((cb >> 24) & 255)};
    float* __restrict__ mfb = out + OFF_MASKF + b * (NCLS * HW) + y * W + x;

    // A2: own-group seg from LDS labels, F-mask stores interleaved (5/dy).
    float segf[4] = {}, segb[4] = {};
#pragma unroll
    for (int dy = 0; dy < 5; ++dy) {
#pragma unroll
        for (int kk = 0; kk < 5; ++kk) {
            const int k = dy * 5 + kk;
            nt_store4(mfb + k * HW, lfa[0] == k ? 1.f : 0.f, lfa[1] == k ? 1.f : 0.f,
                      lfa[2] == k ? 1.f : 0.f, lfa[3] == k ? 1.f : 0.f);
        }
        const int sr = r_i + dy + 2;   // staged row for global y+dy-2
        const unsigned f0 = labs[0][sr][g_i], f1 = labs[0][sr][g_i + 1],
                       f2 = labs[0][sr][g_i + 2];
        const unsigned h0 = labs[1][sr][g_i], h1 = labs[1][sr][g_i + 1],
                       h2 = labs[1][sr][g_i + 2];
        int lwF[8], lwB[8];
#pragma unroll
        for (int j = 0; j < 8; ++j) {
            const int bo = 2 + j;            // byte in the 12-byte window
            const unsigned wf = (bo < 4) ? f0 : (bo < 8 ? f1 : f2);
            const unsigned wb = (bo < 4) ? h0 : (bo < 8 ? h1 : h2);
            const int sh = (bo & 3) * 8;
            lwF[j] = (int)((wf >> sh) & 255);
            lwB[j] = (int)((wb >> sh) & 255);
        }
#pragma unroll
        for (int dx = 0; dx < 5; ++dx) {
            const int base = (dy * 5 + dx) * 26;
#pragma unroll
            for (int i = 0; i < 4; ++i) {
                segf[i] += sk[base + lwF[i + dx]];
                segb[i] += sk[base + lwB[i + dx]];
            }
        }
    }

    // A3: appear -> packed LDS; aux outputs (nt); attn in registers.
    float my_at[4];
    {
        f32x4 pf, pb;
        float af[4], ab[4];
#pragma unroll
        for (int i = 0; i < 4; ++i) {
            af[i] = fmaxf(1.f - fmaxf(segf[i] - 1.f, 0.f), 0.f);
            ab[i] = fmaxf(1.f - fmaxf(segb[i] - 1.f, 0.f), 0.f);
            pf[i] = 2.f * (float)lfa[i] + af[i];
            pb[i] = 2.f * (float)lba[i] + ab[i];
            const float scf = 1.f - fmaxf(1.f - segf[i], 0.f);
            const float scb = 1.f - fmaxf(1.f - segb[i], 0.f);
            my_at[i] = (scf + 1e-5f) / (scf + scb + 2e-5f);
        }
        *reinterpret_cast<f32x4*>(&pF[r_i + 2][4 + x]) = pf;
        *reinterpret_cast<f32x4*>(&pB[r_i + 2][4 + x]) = pb;
        nt_store4(out + OFF_OMAF + pix, 1.f - af[0], 1.f - af[1], 1.f - af[2], 1.f - af[3]);
        nt_store4(out + OFF_OMAB + pix, 1.f - ab[0], 1.f - ab[1], 1.f - ab[2], 1.f - ab[3]);
        nt_store4(out + OFF_ATTN + pix, my_at[0], my_at[1], my_at[2], my_at[3]);
        nt_store4(out + OFF_OMATTN + pix, 1.f - my_at[0], 1.f - my_at[1], 1.f - my_at[2],
                  1.f - my_at[3]);
    }

    // A4: halo from LDS labels — 384 threads, one 2-px unit each (rows {0,1,14,15}).
    if (t < 384) {
        const int hrow = t / 96;
        const int row = (hrow < 2) ? hrow : hrow + TY;   // {0,1,14,15}
        const int hg = t % 96;
        const int xs = 2 * hg;
        const int q = xs >> 2;
        const int off0 = (xs & 3) + 2;
        float sf[2] = {0.f, 0.f}, sb[2] = {0.f, 0.f};
#pragma unroll
        for (int dyh = 0; dyh < 5; ++dyh) {
            const int sr = row + dyh;    // staged row for global y0+row-4+dyh
            const unsigned f0 = labs[0][sr][q], f1 = labs[0][sr][q + 1],
                           f2 = labs[0][sr][q + 2];
            const unsigned h0 = labs[1][sr][q], h1 = labs[1][sr][q + 1],
                           h2 = labs[1][sr][q + 2];
            int lf6[6], lb6[6];
#pragma unroll
            for (int j = 0; j < 6; ++j) {
                const int bo = off0 + j;
                const unsigned wf = (bo < 4) ? f0 : (bo < 8 ? f1 : f2);
                const unsigned wb = (bo < 4) ? h0 : (bo < 8 ? h1 : h2);
                const int sh = (bo & 3) * 8;
                lf6[j] = (int)((wf >> sh) & 255);
                lb6[j] = (int)((wb >> sh) & 255);
            }
#pragma unroll
            for (int dx = 0; dx < 5; ++dx) {
                const int base = (dyh * 5 + dx) * 26;
                sf[0] += sk[base + lf6[dx]];
                sf[1] += sk[base + lf6[dx + 1]];
                sb[0] += sk[base + lb6[dx]];
                sb[1] += sk[base + lb6[dx + 1]];
            }
        }
        // center labels of this 2-px unit (bytes xs+4, xs+5 of staged row row+2)
        const unsigned cf2 = labs[0][row + 2][q + 1];
        const unsigned cb2 = labs[1][row + 2][q + 1];
        const int shc = (xs & 3) * 8;
        const int lf2[2] = {(int)((cf2 >> shc) & 255), (int)((cf2 >> (shc + 8)) & 255)};
        const int lb2[2] = {(int)((cb2 >> shc) & 255), (int)((cb2 >> (shc + 8)) & 255)};
        f32x2 pf2, pb2;
#pragma unroll
        for (int i = 0; i < 2; ++i) {
            const float af = fmaxf(1.f - fmaxf(sf[i] - 1.f, 0.f), 0.f);
            const float ab = fmaxf(1.f - fmaxf(sb[i] - 1.f, 0.f), 0.f);
            pf2[i] = 2.f * (float)lf2[i] + af;
            pb2[i] = 2.f * (float)lb2[i] + ab;
        }
        *reinterpret_cast<f32x2*>(&pF[row][4 + xs]) = pf2;
        *reinterpret_cast<f32x2*>(&pB[row][4 + xs]) = pb2;
    }

    // A5: sentinel side pads.
    if (t < 64) {
        const int arr = t & 1, side = (t >> 1) & 1, row = t >> 2;  // row 0..15
        f32x4 s = {SENT, SENT, SENT, SENT};
        float* dst = arr ? &pB[row][side ? W + 4 : 0] : &pF[row][side ? W + 4 : 0];
        *reinterpret_cast<f32x4*>(dst) = s;
    }

    // ===== lgkm-only barrier: nt stores keep draining across it =====
    __builtin_amdgcn_sched_barrier(0);
    asm volatile("s_waitcnt lgkmcnt(0)" ::: "memory");
    __builtin_amdgcn_s_barrier();
    __builtin_amdgcn_sched_barrier(0);
    asm volatile("" ::: "memory");

    // ================= Phase B: conv + B-mask stores interleaved =================
    float accF[3][4] = {};
    float accB[3][4] = {};
    conv_img<false>(pF, imF, sk, lfa, nullptr, b, y, x, r_i, g_i, accF);
    conv_img<true>(pB, imB, sk, lba, out + OFF_MASKB + b * (NCLS * HW) + y * W + x,
                   b, y, x, r_i, g_i, accB);

    float* pout = out + OFF_PRED + b * (3 * HW) + y * W + x;
#pragma unroll
    for (int c = 0; c < 3; ++c) {
        float p[4];
#pragma unroll
        for (int i = 0; i < 4; ++i)
            p[i] = my_at[i] * accF[c][i] + (1.f - my_at[i]) * accB[c][i];
        nt_store4(pout + c * HW, p[0], p[1], p[2], p[3]);
    }
}

extern "C" void kernel_launch(void* const* d_in, const int* in_sizes, int n_in,
                              void* d_out, int out_size, void* d_ws, size_t ws_size,
                              hipStream_t stream) {
    const float* imF  = (const float*)d_in[0];
    const float* imB  = (const float*)d_in[1];
    const int*   labF = (const int*)d_in[2];
    const int*   labB = (const int*)d_in[3];
    const float* mk   = (const float*)d_in[4];
    float* out = (float*)d_out;

    k_fused<<<NBLK, NTHR, 0, stream>>>(imF, imB, labF, labB, mk, out);
}